// Round 1
// baseline (2729.588 us; speedup 1.0000x reference)
//
#include <hip/hip_runtime.h>
#include <cstdint>
#include <cstddef>

// Problem constants
#define NB    64      // batch
#define NS    4096    // seq len (x_logits width)
#define NH    1024    // hidden
#define NOPSN 8
#define NSTEP 10

#define GRID  256
#define TPB   256

// Workspace layout (float offsets). Total ~13.1 MB.
#define OFF_H    0u        // h        [64][1024]
#define OFF_HN   65536u    // h_n      [64][1024]
#define OFF_PX   131072u   // px partials [8][64][4096]  (x_logits split-K)
#define OFF_PC   2228224u  // pc partials [16][64][1024] (W_res split-K)
#define OFF_CTRL 3276800u  // int ctrl area
// ctrl ints: [0]=magic [1]=barrier cnt [2..11]=stopcnt[t] [16..26]=done[t] [32..95]=ptr[b]
#define MAGIC    0x1357A5E5

__device__ __forceinline__ float bcastf(float v, int l) {
  return __int_as_float(__builtin_amdgcn_readlane(__float_as_int(v), l));
}

// Device-scope grid barrier. Safe: 256 blocks, __launch_bounds__(256,1)
// guarantees >=1 block/CU schedulable on 256 CUs -> all blocks resident.
__device__ __forceinline__ void gridbar(int* cnt, int target) {
  __syncthreads();
  if (threadIdx.x == 0) {
    __threadfence();  // release prior writes (device scope)
    __hip_atomic_fetch_add(cnt, 1, __ATOMIC_RELAXED, __HIP_MEMORY_SCOPE_AGENT);
    while (__hip_atomic_load(cnt, __ATOMIC_RELAXED, __HIP_MEMORY_SCOPE_AGENT) < target)
      __builtin_amdgcn_s_sleep(1);
    __threadfence();  // acquire
  }
  __syncthreads();
}

__global__ void __launch_bounds__(TPB, 1)
sys1_kernel(const float* __restrict__ s2a,  const float* __restrict__ Wres,
            const float* __restrict__ bres, const float* __restrict__ Wop,
            const float* __restrict__ bop,  const float* __restrict__ Wx,
            const float* __restrict__ bx,   const float* __restrict__ noise,
            float* __restrict__ out,        float* __restrict__ wsf)
{
  float* __restrict__ h  = wsf + OFF_H;
  float* __restrict__ hn = wsf + OFF_HN;
  float* __restrict__ px = wsf + OFF_PX;
  float* __restrict__ pc = wsf + OFF_PC;
  int* ctrl = (int*)(wsf + OFF_CTRL);
  int* cnt  = ctrl + 1;

  const int tid = threadIdx.x;
  const int blk = blockIdx.x;

  // ---- bootstrap: block 0 inits ctrl (ws is poisoned 0xAA every launch) ----
  if (blk == 0 && tid == 0) {
    #pragma unroll
    for (int i = 1; i < 32; ++i) ctrl[i] = 0;
    __threadfence();
    __hip_atomic_store(&ctrl[0], (int)MAGIC, __ATOMIC_RELEASE, __HIP_MEMORY_SCOPE_AGENT);
  }
  if (tid == 0) {
    while (__hip_atomic_load(&ctrl[0], __ATOMIC_RELAXED, __HIP_MEMORY_SCOPE_AGENT) != (int)MAGIC)
      __builtin_amdgcn_s_sleep(1);
    __threadfence();
  }
  __syncthreads();

  // ---- init: h = 0, h_n = 0 + 0.01*noise[0] ----
  {
    int idx = blk * TPB + tid;          // exactly 65536 threads
    h[idx]  = 0.f;
    hn[idx] = 0.01f * noise[idx];
  }
  int ep = 0;
  gridbar(cnt, ++ep * GRID);

  const int lane = tid & 63;
  const int wv   = (blk << 2) | (tid >> 6);   // wave id 0..1023

  for (int t = 0; t < NSTEP; ++t) {

    // =========== Phase B: x_logits partials.  lane = s column ===========
    // wave -> (s-group 0..63, k-slice 0..7 of 128, b-half 0..1 of 32)
    {
      const int sg = wv & 63, r = wv >> 6;
      const int ksl = r & 7, bh = r >> 3;
      const int s = (sg << 6) | lane;
      const int k0 = ksl << 7;
      const int bbase = bh << 5;
      float acc[32];
      #pragma unroll
      for (int i = 0; i < 32; ++i) acc[i] = 0.f;

      #pragma unroll 1
      for (int kc = 0; kc < 128; kc += 32) {
        float w[32];
        const float* wp = Wx + (size_t)(k0 + kc) * NS + s;
        #pragma unroll
        for (int kk = 0; kk < 32; ++kk) w[kk] = wp[(size_t)kk * NS];

        const float* hb = hn + (size_t)bbase * NH + (k0 + kc) + (lane & 31);
        float h0n = hb[0], h1n = hb[NH];
        #pragma unroll
        for (int bi = 0; bi < 32; bi += 2) {
          float h0 = h0n, h1 = h1n;
          if (bi + 2 < 32) { h0n = hb[(size_t)(bi + 2) * NH]; h1n = hb[(size_t)(bi + 3) * NH]; }
          float a0 = acc[bi], a1 = acc[bi + 1];
          #pragma unroll
          for (int kk = 0; kk < 32; ++kk) {
            a0 += bcastf(h0, kk) * w[kk];   // v_readlane -> v_fmac (sgpr operand)
            a1 += bcastf(h1, kk) * w[kk];
          }
          acc[bi] = a0; acc[bi + 1] = a1;
        }
      }
      float* po = px + (size_t)(ksl * NB + bbase) * NS + s;
      #pragma unroll
      for (int bi = 0; bi < 32; ++bi) po[(size_t)bi * NS] = acc[bi];
    }
    gridbar(cnt, ++ep * GRID);

    // =========== Phase R: per-b argmax over S + op logits (blocks 0..63) ===========
    if (blk < NB) {
      const int b = blk;
      float bestv = -3.402823466e+38f; int besti = 0;
      for (int so = 0; so < NS; so += TPB) {
        int s = so + tid;
        float v = bx[s];
        #pragma unroll
        for (int sl = 0; sl < 8; ++sl) v += px[(size_t)(sl * NB + b) * NS + s];
        if (v > bestv) { bestv = v; besti = s; }   // ascending s -> first-max
      }
      __shared__ float rv[TPB];
      __shared__ int   rix[TPB];
      rv[tid] = bestv; rix[tid] = besti;
      __syncthreads();
      for (int str = TPB / 2; str > 0; str >>= 1) {
        if (tid < str) {
          float ov = rv[tid + str]; int oi = rix[tid + str];
          if (ov > rv[tid] || (ov == rv[tid] && oi < rix[tid])) { rv[tid] = ov; rix[tid] = oi; }
        }
        __syncthreads();
      }
      // op logits: hn[b] . W_op  (8 outputs)
      float op[8];
      #pragma unroll
      for (int o = 0; o < 8; ++o) op[o] = 0.f;
      for (int k = tid; k < NH; k += TPB) {
        float hv = hn[(size_t)b * NH + k];
        const float* wr = Wop + (size_t)k * NOPSN;
        #pragma unroll
        for (int o = 0; o < 8; ++o) op[o] += hv * wr[o];
      }
      __shared__ float rop[8][TPB];
      #pragma unroll
      for (int o = 0; o < 8; ++o) rop[o][tid] = op[o];
      __syncthreads();
      for (int str = TPB / 2; str > 0; str >>= 1) {
        if (tid < str) {
          #pragma unroll
          for (int o = 0; o < 8; ++o) rop[o][tid] += rop[o][tid + str];
        }
        __syncthreads();
      }
      if (tid == 0) {
        int ip = rix[0]; if (ip > NS - 1) ip = NS - 1;
        ctrl[32 + b] = ip;
        float bv = rop[0][0] + bop[0]; int bo = 0;
        #pragma unroll
        for (int o = 1; o < 8; ++o) {
          float v = rop[o][0] + bop[o];
          if (v > bv) { bv = v; bo = o; }          // strict > : first-max
        }
        if (bo == 0) atomicAdd(&ctrl[2 + t], 1);
      }
    }
    gridbar(cnt, ++ep * GRID);

    // =========== Phase C: h_new partials = concat(h_n, s2a[b][ptr[b]]) @ W_res ===========
    // wave -> (j-group 0..15, k-slice 0..15 of 128 over K=2048, b-quarter 0..3 of 16)
    {
      const int jg = wv & 15, r = wv >> 4;
      const int ksl = r & 15, bsel = r >> 4;
      const int j = (jg << 6) | lane;
      const int k0 = ksl << 7;
      const int bbase = bsel << 4;
      float acc[16];
      #pragma unroll
      for (int i = 0; i < 16; ++i) acc[i] = 0.f;

      #pragma unroll 1
      for (int kc = 0; kc < 128; kc += 32) {
        float w[32];
        const float* wp = Wres + (size_t)(k0 + kc) * NH + j;
        #pragma unroll
        for (int kk = 0; kk < 32; ++kk) w[kk] = wp[(size_t)kk * NH];

        const int kk0 = k0 + kc;
        auto srcp = [&](int b) -> const float* {
          if (kk0 < NH) return hn + (size_t)b * NH + kk0 + (lane & 31);
          int p = ctrl[32 + b];
          return s2a + ((size_t)b * NS + p) * NH + (kk0 - NH) + (lane & 31);
        };
        float h0n = *srcp(bbase), h1n = *srcp(bbase + 1);
        #pragma unroll
        for (int bi = 0; bi < 16; bi += 2) {
          float h0 = h0n, h1 = h1n;
          if (bi + 2 < 16) { h0n = *srcp(bbase + bi + 2); h1n = *srcp(bbase + bi + 3); }
          float a0 = acc[bi], a1 = acc[bi + 1];
          #pragma unroll
          for (int kk = 0; kk < 32; ++kk) {
            a0 += bcastf(h0, kk) * w[kk];
            a1 += bcastf(h1, kk) * w[kk];
          }
          acc[bi] = a0; acc[bi + 1] = a1;
        }
      }
      float* po = pc + (size_t)(ksl * NB + bbase) * NH + j;
      #pragma unroll
      for (int bi = 0; bi < 16; ++bi) po[(size_t)bi * NH] = acc[bi];
    }
    gridbar(cnt, ++ep * GRID);

    // =========== Phase D: reduce partials, done/freeze logic, next h_n ===========
    {
      const int idx = blk * TPB + tid;       // 0..65535
      const int b = idx >> 10, j = idx & 1023;
      float v = bres[j];
      #pragma unroll
      for (int sl = 0; sl < 16; ++sl) v += pc[(size_t)(sl * NB + b) * NH + j];
      int done = ctrl[16 + t];
      float hcur = h[idx];
      float hout = done ? hcur : v;
      h[idx] = hout;
      if (t < NSTEP - 1) hn[idx] = hout + 0.01f * noise[(size_t)(t + 1) * (NB * NH) + idx];
      else out[idx] = hout;
      if (idx == 0) {
        int stop = ctrl[2 + t];
        ctrl[16 + t + 1] = done | (stop == NB ? 1 : 0);
      }
    }
    if (t < NSTEP - 1) gridbar(cnt, ++ep * GRID);
  }
}

extern "C" void kernel_launch(void* const* d_in, const int* in_sizes, int n_in,
                              void* d_out, int out_size, void* d_ws, size_t ws_size,
                              hipStream_t stream) {
  const float* s2a   = (const float*)d_in[0];
  const float* Wres  = (const float*)d_in[1];
  const float* bres  = (const float*)d_in[2];
  const float* Wop   = (const float*)d_in[3];
  const float* bop   = (const float*)d_in[4];
  const float* Wx    = (const float*)d_in[5];
  const float* bx    = (const float*)d_in[6];
  const float* noise = (const float*)d_in[7];
  float* outp = (float*)d_out;
  float* wsf  = (float*)d_ws;   // needs ~13.2 MB
  hipLaunchKernelGGL(sys1_kernel, dim3(GRID), dim3(TPB), 0, stream,
                     s2a, Wres, bres, Wop, bop, Wx, bx, noise, outp, wsf);
}